// Round 4
// baseline (851.790 us; speedup 1.0000x reference)
//
#include <hip/hip_runtime.h>

typedef __attribute__((ext_vector_type(8))) unsigned short us8;
typedef __attribute__((ext_vector_type(4))) unsigned short us4;
typedef __attribute__((ext_vector_type(2))) unsigned short us2;
typedef __attribute__((ext_vector_type(8))) short s8;
typedef __attribute__((ext_vector_type(4))) float f4;

#define DEV static __device__ __forceinline__

DEV float bf2f(unsigned short h){ return __uint_as_float(((unsigned)h)<<16); }
DEV unsigned short f2bf(float f){
  unsigned x = __float_as_uint(f);
  x += 0x7fffu + ((x>>16)&1u);
  return (unsigned short)(x>>16);
}
DEV float sigm(float x){ return 1.f/(1.f + __expf(-x)); }

// ---------------- setup kernels ----------------
__global__ void k_zero_int(int* p, int n){
  int i = blockIdx.x*blockDim.x+threadIdx.x; if(i<n) p[i]=0;
}

__global__ void k_hist(const int* __restrict__ dst, int* __restrict__ degi, int e){
  int i = blockIdx.x*blockDim.x+threadIdx.x;
  if(i<e) atomicAdd(&degi[dst[i]], 1);
}

__global__ void k_dinv(const int* __restrict__ degi, float* __restrict__ dinv, int n){
  int i = blockIdx.x*blockDim.x+threadIdx.x;
  if(i<n) dinv[i] = rsqrtf((float)degi[i] + 1.0f);
}

__global__ void k_scan_part(const int* __restrict__ deg, int* __restrict__ rowp,
                            int* __restrict__ part, int n){
  __shared__ int sd[256];
  int t = threadIdx.x, blk = blockIdx.x;
  int base = blk*1024 + t*4;
  int v[4], tot = 0;
  #pragma unroll
  for(int j=0;j<4;++j){ v[j] = (base+j<n) ? deg[base+j] : 0; tot += v[j]; }
  sd[t] = tot; __syncthreads();
  for(int off=1; off<256; off<<=1){
    int x = (t>=off) ? sd[t-off] : 0;
    __syncthreads();
    sd[t] += x;
    __syncthreads();
  }
  int excl = sd[t] - tot;
  if(t==255) part[blk] = sd[t];
  int run = excl;
  #pragma unroll
  for(int j=0;j<4;++j){ if(base+j<n) rowp[base+j] = run; run += v[j]; }
}

__global__ void k_scan_top(int* part, int nb){
  if(threadIdx.x==0 && blockIdx.x==0){
    int run = 0;
    for(int i=0;i<nb;++i){ int v = part[i]; part[i] = run; run += v; }
  }
}

__global__ void k_scan_add(int* __restrict__ rowp, const int* __restrict__ part, int n){
  int blk = blockIdx.x, t = threadIdx.x;
  int add = part[blk];
  int base = blk*1024 + t*4;
  #pragma unroll
  for(int j=0;j<4;++j) if(base+j<n) rowp[base+j] += add;
}

__global__ void k_fill(const int* __restrict__ src, const int* __restrict__ dst,
                       const int* __restrict__ rowp, int* __restrict__ cnt,
                       int* __restrict__ col, int e){
  int i = blockIdx.x*blockDim.x+threadIdx.x;
  if(i<e){
    int d = dst[i];
    int pos = rowp[d] + atomicAdd(&cnt[d],1);
    col[pos] = src[i];
  }
}

// sort each adjacency list ascending by src id (locality transform only —
// correctness does not depend on order). LDS insertion sort, 1 thread/node.
#define SCAP 96
__global__ __launch_bounds__(128) void k_sortrows(const int* __restrict__ rowp,
    const int* __restrict__ degi, int* __restrict__ col, int n){
  __shared__ int buf[128*97];
  int node = blockIdx.x*128 + threadIdx.x;
  if(node>=n) return;
  int start = rowp[node], cnt = degi[node];
  if(cnt<=1) return;
  if(cnt<=SCAP){
    int* a = buf + threadIdx.x*97;
    for(int i=0;i<cnt;++i) a[i] = col[start+i];
    for(int i=1;i<cnt;++i){
      int key=a[i]; int j=i-1;
      while(j>=0 && a[j]>key){ a[j+1]=a[j]; --j; }
      a[j+1]=key;
    }
    for(int i=0;i<cnt;++i) col[start+i] = a[i];
  } else {
    for(int i=1;i<cnt;++i){
      int key=col[start+i]; int j=i-1;
      while(j>=0 && col[start+j]>key){ col[start+j+1]=col[start+j]; --j; }
      col[start+j+1]=key;
    }
  }
}

// transpose + bf16-cast the 12 weight matrices: WT[m][j][k] = W[m][k][j]
__global__ void k_prepw(const float* __restrict__ Wx, const float* __restrict__ Wh,
                        unsigned short* __restrict__ WT, int total){
  int i = blockIdx.x*blockDim.x+threadIdx.x;
  if(i>=total) return;
  int m = i >> 14;
  int rem = i & 16383;
  int j = rem >> 7;     // output column
  int k = rem & 127;    // k index
  const float* W = (m<6) ? (Wx + (size_t)m*16384) : (Wh + (size_t)(m-6)*16384);
  WT[(size_t)m*16384 + rem] = f2bf(W[(size_t)k*128 + j]);
}

// ---------------- per-layer kernels ----------------
// y2[n,0:128] = bf16(dinv[n]*inp[n]);  y2[n,128:256] = bf16(dinv[n]*h_l[n])
__global__ void k_scale2(const float* __restrict__ inp, const float* __restrict__ hl,
                         const float* __restrict__ dinv, unsigned short* __restrict__ y2, int n){
  int i = blockIdx.x*blockDim.x+threadIdx.x;
  if(i >= n*32) return;
  int node = i>>5, d0 = (i&31)*4;
  float dv = dinv[node];
  f4 a = *(const f4*)(inp + (size_t)node*128 + d0);
  f4 b = *(const f4*)(hl  + (size_t)node*128 + d0);
  us4 wa, wb;
  #pragma unroll
  for(int j=0;j<4;++j){ wa[j] = f2bf(dv*a[j]); wb[j] = f2bf(dv*b[j]); }
  *(us4*)(y2 + (size_t)node*256 + d0)       = wa;
  *(us4*)(y2 + (size_t)node*256 + 128 + d0) = wb;
}

// CSR aggregation: out = bf16( dinv[n] * ( y[n] + sum_{src->n} y[src] ) )
// NV = bf16 elems per lane (2 -> D=128, 4 -> D=256 split into out0/out1)
template<int NV>
__global__ __launch_bounds__(256) void k_agg(const unsigned short* __restrict__ y,
    const int* __restrict__ rowp, const int* __restrict__ degi, const int* __restrict__ col,
    const float* __restrict__ dinv, unsigned short* __restrict__ out0,
    unsigned short* __restrict__ out1, int n)
{
  constexpr int D = NV*64;
  constexpr int U = (NV==2) ? 16 : 8;
  int lane = threadIdx.x & 63;
  int node = blockIdx.x*4 + (threadIdx.x>>6);
  if(node >= n) return;
  const unsigned short* ybase = y + (size_t)lane*NV;
  float acc[NV];
  {
    const unsigned short* p = ybase + (size_t)node*D;
    if constexpr(NV==2){ us2 v = *(const us2*)p; acc[0]=bf2f(v[0]); acc[1]=bf2f(v[1]); }
    else { us4 v = *(const us4*)p;
      #pragma unroll
      for(int j=0;j<4;++j) acc[j]=bf2f(v[j]); }
  }
  int start = rowp[node];
  int cnt = degi[node];
  int last = cnt - 1;
  for(int i=0; i<cnt; i += U){
    int s[U];
    #pragma unroll
    for(int u=0;u<U;++u){
      int ii = i + u; ii = (ii < last) ? ii : last;
      s[u] = col[start + ii];
    }
    if constexpr(NV==2){
      us2 v[U];
      #pragma unroll
      for(int u=0;u<U;++u) v[u] = *(const us2*)(ybase + (size_t)s[u]*D);
      #pragma unroll
      for(int u=0;u<U;++u){
        if(i + u < cnt){ acc[0]+=bf2f(v[u][0]); acc[1]+=bf2f(v[u][1]); }
      }
    } else {
      us4 v[U];
      #pragma unroll
      for(int u=0;u<U;++u) v[u] = *(const us4*)(ybase + (size_t)s[u]*D);
      #pragma unroll
      for(int u=0;u<U;++u){
        if(i + u < cnt){
          #pragma unroll
          for(int j=0;j<4;++j) acc[j]+=bf2f(v[u][j]);
        }
      }
    }
  }
  float dv = dinv[node];
  if constexpr(NV==2){
    us2 w; w[0]=f2bf(acc[0]*dv); w[1]=f2bf(acc[1]*dv);
    *(us2*)(out0 + (size_t)node*128 + lane*2) = w;
  } else {
    us4 w;
    #pragma unroll
    for(int j=0;j<4;++j) w[j]=f2bf(acc[j]*dv);
    int c = lane*4;
    unsigned short* o = (c<128) ? (out0 + (size_t)node*128 + c)
                                : (out1 + (size_t)node*128 + (c-128));
    *(us4*)o = w;
  }
}

// 128x128-tile GEMM (rows x 128 cols), bf16 MFMA, optional 2nd channel.
// MODE 0: Z[row*256 + zcol + col] = acc
// MODE 1: yq[row*128+col] = bf16( dinv[row] * sigm(acc + b1[col]+b2[col]) * hl[row,col] )
// MODE 2: z = sigm(Z[row*256+col] + b1+b2); ht = tanh(acc + Z[row*256+128+col] + b3+b4)
//         outp[row*128+col] = z*hl + (1-z)*ht
template<int MODE>
__global__ __launch_bounds__(256) void k_gemm(const unsigned short* __restrict__ A1,
    const unsigned short* __restrict__ A2, const unsigned short* __restrict__ B1,
    const unsigned short* __restrict__ B2, float* __restrict__ Z, int zcol,
    const float* __restrict__ hl, const float* __restrict__ dinv,
    const float* __restrict__ b1, const float* __restrict__ b2,
    const float* __restrict__ b3, const float* __restrict__ b4,
    unsigned short* __restrict__ yq, float* __restrict__ outp, int nrows)
{
  __shared__ unsigned short As[128*136];
  __shared__ unsigned short Bs[128*136];
  const int t = threadIdx.x;
  const int lane = t & 63;
  const int lo = lane & 15, hi = lane >> 4;
  const int wid = t >> 6;
  const int wr = wid >> 1, wc = wid & 1;
  const int brow = blockIdx.x * 128;
  f4 acc[4][4];
  #pragma unroll
  for(int m=0;m<4;++m)
    #pragma unroll
    for(int n=0;n<4;++n) acc[m][n] = (f4)0.f;

  const int nch = A2 ? 2 : 1;
  for(int ch=0; ch<nch; ++ch){
    const unsigned short* A = ch ? A2 : A1;
    const unsigned short* B = ch ? B2 : B1;
    __syncthreads();
    #pragma unroll
    for(int i=0;i<8;++i){
      int c = t + i*256;          // 0..2047 chunks of 8 bf16
      int r = c >> 4, k0 = (c & 15)*8;
      us8 va = (us8)0;
      int gr = brow + r;
      if (gr < nrows) va = *(const us8*)(A + (size_t)gr*128 + k0);
      *(us8*)(&As[r*136 + k0]) = va;
      us8 vb = *(const us8*)(B + (size_t)c*8);
      *(us8*)(&Bs[r*136 + k0]) = vb;
    }
    __syncthreads();
    #pragma unroll
    for(int kk=0;kk<4;++kk){
      s8 af[4], bfr[4];
      #pragma unroll
      for(int m=0;m<4;++m)
        af[m] = *(const s8*)(&As[(wr*64 + m*16 + lo)*136 + kk*32 + hi*8]);
      #pragma unroll
      for(int n=0;n<4;++n)
        bfr[n] = *(const s8*)(&Bs[(wc*64 + n*16 + lo)*136 + kk*32 + hi*8]);
      #pragma unroll
      for(int m=0;m<4;++m)
        #pragma unroll
        for(int n=0;n<4;++n)
          acc[m][n] = __builtin_amdgcn_mfma_f32_16x16x32_bf16(af[m], bfr[n], acc[m][n], 0,0,0);
    }
  }

  const int c0 = wc*64;
  #pragma unroll
  for(int n=0;n<4;++n){
    const int colv = c0 + n*16 + lo;
    float bz = 0.f, bh = 0.f;
    if constexpr(MODE==1){ bz = b1[colv] + b2[colv]; }
    if constexpr(MODE==2){ bz = b1[colv] + b2[colv]; bh = b3[colv] + b4[colv]; }
    #pragma unroll
    for(int m=0;m<4;++m){
      int rbase = brow + wr*64 + m*16 + hi*4;
      #pragma unroll
      for(int tt=0;tt<4;++tt){
        int row = rbase + tt;
        if(row >= nrows) continue;
        float v = acc[m][n][tt];
        if constexpr(MODE==0){
          Z[(size_t)row*256 + zcol + colv] = v;
        } else if constexpr(MODE==1){
          float r = sigm(v + bz);
          yq[(size_t)row*128 + colv] = f2bf(dinv[row] * r * hl[(size_t)row*128 + colv]);
        } else {
          float z  = sigm(Z[(size_t)row*256 + colv] + bz);
          float ht = tanhf(v + Z[(size_t)row*256 + 128 + colv] + bh);
          outp[(size_t)row*128 + colv] = z*hl[(size_t)row*128 + colv] + (1.f - z)*ht;
        }
      }
    }
  }
}

extern "C" void kernel_launch(void* const* d_in, const int* in_sizes, int n_in,
                              void* d_out, int out_size, void* d_ws, size_t ws_size,
                              hipStream_t stream){
  const float* x  = (const float*)d_in[0];
  const int*   ei = (const int*)d_in[1];
  const float* h  = (const float*)d_in[2];
  const float* Wx = (const float*)d_in[3];
  const float* bx = (const float*)d_in[4];
  const float* Wh = (const float*)d_in[5];
  const float* bh = (const float*)d_in[6];
  float* out = (float*)d_out;

  const int N = in_sizes[0] / 128;
  const int E = in_sizes[1] / 2;
  const int L = in_sizes[2] / in_sizes[0];
  const int* src = ei;
  const int* dst = ei + E;

  char* w = (char*)d_ws;
  auto alloc = [&](size_t b)->char*{ char* p = w; w += (b + 255) & ~(size_t)255; return p; };
  int* degi = (int*)alloc((size_t)2*N*sizeof(int)); int* cnt = degi + N;
  int* rowp = (int*)alloc((size_t)N*sizeof(int));
  int* part = (int*)alloc(256*sizeof(int));
  int* col  = (int*)alloc((size_t)E*sizeof(int));
  float* dinv = (float*)alloc((size_t)N*sizeof(float));
  unsigned short* WT = (unsigned short*)alloc((size_t)12*16384*sizeof(short));
  unsigned short* y2 = (unsigned short*)alloc((size_t)N*256*sizeof(short));
  unsigned short* ax = (unsigned short*)alloc((size_t)N*128*sizeof(short));
  unsigned short* ah = (unsigned short*)alloc((size_t)N*128*sizeof(short));
  unsigned short* yq = (unsigned short*)alloc((size_t)N*128*sizeof(short));
  unsigned short* aq = (unsigned short*)alloc((size_t)N*128*sizeof(short));
  float* Zpre = (float*)alloc((size_t)N*256*sizeof(float));

  const int NB = (N + 1023)/1024;
  const int gE = (E + 255)/256;
  const int gN = (N + 255)/256;
  const int gew = (N*32 + 255)/256;
  const int gagg = (N + 3)/4;
  const int grows = (N + 127)/128;

  k_zero_int<<<(2*N+255)/256,256,0,stream>>>(degi, 2*N);
  k_hist<<<gE,256,0,stream>>>(dst, degi, E);
  k_dinv<<<gN,256,0,stream>>>(degi, dinv, N);
  k_scan_part<<<NB,256,0,stream>>>(degi, rowp, part, N);
  k_scan_top<<<1,64,0,stream>>>(part, NB);
  k_scan_add<<<NB,256,0,stream>>>(rowp, part, N);
  k_fill<<<gE,256,0,stream>>>(src, dst, rowp, cnt, col, E);
  k_sortrows<<<(N+127)/128,128,0,stream>>>(rowp, degi, col, N);
  k_prepw<<<(12*16384+255)/256,256,0,stream>>>(Wx, Wh, WT, 12*16384);

  for(int l=0; l<L; ++l){
    const float* inp = (l==0) ? x : (out + (size_t)(l-1)*N*128);
    const float* hl  = h + (size_t)l*N*128;
    const float* bxz = bx + (size_t)(l*3+0)*128; const float* bhz = bh + (size_t)(l*3+0)*128;
    const float* bxr = bx + (size_t)(l*3+1)*128; const float* bhr = bh + (size_t)(l*3+1)*128;
    const float* bxh = bx + (size_t)(l*3+2)*128; const float* bhh = bh + (size_t)(l*3+2)*128;
    const unsigned short* Wxz = WT + (size_t)(l*3+0)*16384;
    const unsigned short* Wxr = WT + (size_t)(l*3+1)*16384;
    const unsigned short* Wxh = WT + (size_t)(l*3+2)*16384;
    const unsigned short* Whz = WT + (size_t)(6+l*3+0)*16384;
    const unsigned short* Whr = WT + (size_t)(6+l*3+1)*16384;
    const unsigned short* Whh = WT + (size_t)(6+l*3+2)*16384;

    k_scale2<<<gew,256,0,stream>>>(inp, hl, dinv, y2, N);
    k_agg<4><<<gagg,256,0,stream>>>(y2, rowp, degi, col, dinv, ax, ah, N);
    // z-pre: Z[:,0:128] = ax@Wxz + ah@Whz
    k_gemm<0><<<grows,256,0,stream>>>(ax, ah, Wxz, Whz, Zpre, 0,
                                      nullptr, nullptr, nullptr, nullptr, nullptr, nullptr,
                                      nullptr, nullptr, N);
    // r fused: yq = bf16(dinv * sigm(ax@Wxr + ah@Whr + bxr+bhr) * h)
    k_gemm<1><<<grows,256,0,stream>>>(ax, ah, Wxr, Whr, nullptr, 0,
                                      hl, dinv, bxr, bhr, nullptr, nullptr,
                                      yq, nullptr, N);
    // htpre partial: Z[:,128:256] = ax@Wxh
    k_gemm<0><<<grows,256,0,stream>>>(ax, nullptr, Wxh, nullptr, Zpre, 128,
                                      nullptr, nullptr, nullptr, nullptr, nullptr, nullptr,
                                      nullptr, nullptr, N);
    k_agg<2><<<gagg,256,0,stream>>>(yq, rowp, degi, col, dinv, aq, nullptr, N);
    // final fused: out = z*h + (1-z)*tanh(aq@Whh + Z[:,128:256] + bxh+bhh)
    k_gemm<2><<<grows,256,0,stream>>>(aq, nullptr, Whh, nullptr, Zpre, 0,
                                      hl, dinv, bxz, bhz, bxh, bhh,
                                      nullptr, out + (size_t)l*N*128, N);
  }
}

// Round 5
// 738.761 us; speedup vs baseline: 1.1530x; 1.1530x over previous
//
#include <hip/hip_runtime.h>

typedef __attribute__((ext_vector_type(8))) unsigned short us8;
typedef __attribute__((ext_vector_type(4))) unsigned short us4;
typedef __attribute__((ext_vector_type(2))) unsigned short us2;
typedef __attribute__((ext_vector_type(8))) short s8;
typedef __attribute__((ext_vector_type(4))) float f4;

#define DEV static __device__ __forceinline__

DEV float bf2f(unsigned short h){ return __uint_as_float(((unsigned)h)<<16); }
DEV unsigned short f2bf(float f){
  unsigned x = __float_as_uint(f);
  x += 0x7fffu + ((x>>16)&1u);
  return (unsigned short)(x>>16);
}
DEV float sigm(float x){ return 1.f/(1.f + __expf(-x)); }

// ---------------- setup kernels ----------------
__global__ void k_zero_int(int* p, int n){
  int i = blockIdx.x*blockDim.x+threadIdx.x; if(i<n) p[i]=0;
}

__global__ void k_hist(const int* __restrict__ dst, int* __restrict__ degi, int e){
  int i = blockIdx.x*blockDim.x+threadIdx.x;
  if(i<e) atomicAdd(&degi[dst[i]], 1);
}

__global__ void k_dinv(const int* __restrict__ degi, float* __restrict__ dinv, int n){
  int i = blockIdx.x*blockDim.x+threadIdx.x;
  if(i<n) dinv[i] = rsqrtf((float)degi[i] + 1.0f);
}

__global__ void k_scan_part(const int* __restrict__ deg, int* __restrict__ rowp,
                            int* __restrict__ part, int n){
  __shared__ int sd[256];
  int t = threadIdx.x, blk = blockIdx.x;
  int base = blk*1024 + t*4;
  int v[4], tot = 0;
  #pragma unroll
  for(int j=0;j<4;++j){ v[j] = (base+j<n) ? deg[base+j] : 0; tot += v[j]; }
  sd[t] = tot; __syncthreads();
  for(int off=1; off<256; off<<=1){
    int x = (t>=off) ? sd[t-off] : 0;
    __syncthreads();
    sd[t] += x;
    __syncthreads();
  }
  int excl = sd[t] - tot;
  if(t==255) part[blk] = sd[t];
  int run = excl;
  #pragma unroll
  for(int j=0;j<4;++j){ if(base+j<n) rowp[base+j] = run; run += v[j]; }
}

__global__ void k_scan_top(int* part, int nb){
  if(threadIdx.x==0 && blockIdx.x==0){
    int run = 0;
    for(int i=0;i<nb;++i){ int v = part[i]; part[i] = run; run += v; }
  }
}

__global__ void k_scan_add(int* __restrict__ rowp, const int* __restrict__ part, int n){
  int blk = blockIdx.x, t = threadIdx.x;
  int add = part[blk];
  int base = blk*1024 + t*4;
  #pragma unroll
  for(int j=0;j<4;++j) if(base+j<n) rowp[base+j] += add;
}

__global__ void k_fill(const int* __restrict__ src, const int* __restrict__ dst,
                       const int* __restrict__ rowp, int* __restrict__ cnt,
                       int* __restrict__ col, int e){
  int i = blockIdx.x*blockDim.x+threadIdx.x;
  if(i<e){
    int d = dst[i];
    int pos = rowp[d] + atomicAdd(&cnt[d],1);
    col[pos] = src[i];
  }
}

// transpose + bf16-cast the 12 weight matrices: WT[m][j][k] = W[m][k][j]
__global__ void k_prepw(const float* __restrict__ Wx, const float* __restrict__ Wh,
                        unsigned short* __restrict__ WT, int total){
  int i = blockIdx.x*blockDim.x+threadIdx.x;
  if(i>=total) return;
  int m = i >> 14;
  int rem = i & 16383;
  int j = rem >> 7;     // output column
  int k = rem & 127;    // k index
  const float* W = (m<6) ? (Wx + (size_t)m*16384) : (Wh + (size_t)(m-6)*16384);
  WT[(size_t)m*16384 + rem] = f2bf(W[(size_t)k*128 + j]);
}

// ---------------- per-layer kernels ----------------
// y2[n,0:128] = bf16(dinv[n]*inp[n]);  y2[n,128:256] = bf16(dinv[n]*h_l[n])
__global__ void k_scale2(const float* __restrict__ inp, const float* __restrict__ hl,
                         const float* __restrict__ dinv, unsigned short* __restrict__ y2, int n){
  int i = blockIdx.x*blockDim.x+threadIdx.x;
  if(i >= n*32) return;
  int node = i>>5, d0 = (i&31)*4;
  float dv = dinv[node];
  f4 a = *(const f4*)(inp + (size_t)node*128 + d0);
  f4 b = *(const f4*)(hl  + (size_t)node*128 + d0);
  us4 wa, wb;
  #pragma unroll
  for(int j=0;j<4;++j){ wa[j] = f2bf(dv*a[j]); wb[j] = f2bf(dv*b[j]); }
  *(us4*)(y2 + (size_t)node*256 + d0)       = wa;
  *(us4*)(y2 + (size_t)node*256 + 128 + d0) = wb;
}

// CSR aggregation: out = bf16( dinv[n] * ( y[n] + sum_{src->n} y[src] ) )
// NV=4: D=256, half-wave (32 lanes x 16B) per node.
// NV=2: D=128, quarter-wave (16 lanes x 16B) per node.
// Each wave-instruction gathers 2/4 independent rows -> more lines in flight.
template<int NV>
__global__ __launch_bounds__(256) void k_agg(const unsigned short* __restrict__ y,
    const int* __restrict__ rowp, const int* __restrict__ degi, const int* __restrict__ col,
    const float* __restrict__ dinv, unsigned short* __restrict__ out0,
    unsigned short* __restrict__ out1, int n)
{
  constexpr int D = NV*64;       // row length in bf16
  constexpr int GL = D/8;        // lanes per node-group (8 bf16 per lane)
  constexpr int NG = 64/GL;      // nodes per wave
  constexpr int U = 8;
  int tid = threadIdx.x;
  int wave = tid>>6, lane = tid&63;
  int g = lane/GL, gl = lane%GL;
  int node = blockIdx.x*(4*NG) + wave*NG + g;
  if(node >= n) return;
  const unsigned short* yb = y + (size_t)gl*8;
  float acc[8];
  {
    us8 v0 = *(const us8*)(yb + (size_t)node*D);
    #pragma unroll
    for(int j=0;j<8;++j) acc[j]=bf2f(v0[j]);
  }
  int start = rowp[node];
  int cnt = degi[node];
  int last = cnt - 1;
  for(int i=0; i<cnt; i += U){
    int s[U];
    #pragma unroll
    for(int u=0;u<U;++u){
      int ii = i + u; ii = (ii < last) ? ii : last;
      s[u] = col[start + ii];
    }
    us8 v[U];
    #pragma unroll
    for(int u=0;u<U;++u) v[u] = *(const us8*)(yb + (size_t)s[u]*D);
    #pragma unroll
    for(int u=0;u<U;++u){
      if(i + u < cnt){
        #pragma unroll
        for(int j=0;j<8;++j) acc[j]+=bf2f(v[u][j]);
      }
    }
  }
  float dv = dinv[node];
  us8 w;
  #pragma unroll
  for(int j=0;j<8;++j) w[j]=f2bf(acc[j]*dv);
  int c = gl*8;
  if constexpr(NV==2){
    *(us8*)(out0 + (size_t)node*128 + c) = w;
  } else {
    unsigned short* o = (c<128) ? (out0 + (size_t)node*128 + c)
                                : (out1 + (size_t)node*128 + (c-128));
    *(us8*)o = w;
  }
}

// 128x128-tile GEMM (rows x 128 cols), bf16 MFMA, optional 2nd channel.
// MODE 0: Z[row*256 + zcol + col] = acc
// MODE 1: yq[row*128+col] = bf16( dinv[row] * sigm(acc + b1[col]+b2[col]) * hl[row,col] )
// MODE 2: z = sigm(Z[row*256+col] + b1+b2); ht = tanh(acc + Z[row*256+128+col] + b3+b4)
//         outp[row*128+col] = z*hl + (1-z)*ht
template<int MODE>
__global__ __launch_bounds__(256) void k_gemm(const unsigned short* __restrict__ A1,
    const unsigned short* __restrict__ A2, const unsigned short* __restrict__ B1,
    const unsigned short* __restrict__ B2, float* __restrict__ Z, int zcol,
    const float* __restrict__ hl, const float* __restrict__ dinv,
    const float* __restrict__ b1, const float* __restrict__ b2,
    const float* __restrict__ b3, const float* __restrict__ b4,
    unsigned short* __restrict__ yq, float* __restrict__ outp, int nrows)
{
  __shared__ unsigned short As[128*136];
  __shared__ unsigned short Bs[128*136];
  const int t = threadIdx.x;
  const int lane = t & 63;
  const int lo = lane & 15, hi = lane >> 4;
  const int wid = t >> 6;
  const int wr = wid >> 1, wc = wid & 1;
  const int brow = blockIdx.x * 128;
  f4 acc[4][4];
  #pragma unroll
  for(int m=0;m<4;++m)
    #pragma unroll
    for(int n=0;n<4;++n) acc[m][n] = (f4)0.f;

  const int nch = A2 ? 2 : 1;
  for(int ch=0; ch<nch; ++ch){
    const unsigned short* A = ch ? A2 : A1;
    const unsigned short* B = ch ? B2 : B1;
    __syncthreads();
    #pragma unroll
    for(int i=0;i<8;++i){
      int c = t + i*256;          // 0..2047 chunks of 8 bf16
      int r = c >> 4, k0 = (c & 15)*8;
      us8 va = (us8)0;
      int gr = brow + r;
      if (gr < nrows) va = *(const us8*)(A + (size_t)gr*128 + k0);
      *(us8*)(&As[r*136 + k0]) = va;
      us8 vb = *(const us8*)(B + (size_t)c*8);
      *(us8*)(&Bs[r*136 + k0]) = vb;
    }
    __syncthreads();
    #pragma unroll
    for(int kk=0;kk<4;++kk){
      s8 af[4], bfr[4];
      #pragma unroll
      for(int m=0;m<4;++m)
        af[m] = *(const s8*)(&As[(wr*64 + m*16 + lo)*136 + kk*32 + hi*8]);
      #pragma unroll
      for(int n=0;n<4;++n)
        bfr[n] = *(const s8*)(&Bs[(wc*64 + n*16 + lo)*136 + kk*32 + hi*8]);
      #pragma unroll
      for(int m=0;m<4;++m)
        #pragma unroll
        for(int n=0;n<4;++n)
          acc[m][n] = __builtin_amdgcn_mfma_f32_16x16x32_bf16(af[m], bfr[n], acc[m][n], 0,0,0);
    }
  }

  const int c0 = wc*64;
  #pragma unroll
  for(int n=0;n<4;++n){
    const int colv = c0 + n*16 + lo;
    float bz = 0.f, bh = 0.f;
    if constexpr(MODE==1){ bz = b1[colv] + b2[colv]; }
    if constexpr(MODE==2){ bz = b1[colv] + b2[colv]; bh = b3[colv] + b4[colv]; }
    #pragma unroll
    for(int m=0;m<4;++m){
      int rbase = brow + wr*64 + m*16 + hi*4;
      #pragma unroll
      for(int tt=0;tt<4;++tt){
        int row = rbase + tt;
        if(row >= nrows) continue;
        float v = acc[m][n][tt];
        if constexpr(MODE==0){
          Z[(size_t)row*256 + zcol + colv] = v;
        } else if constexpr(MODE==1){
          float r = sigm(v + bz);
          yq[(size_t)row*128 + colv] = f2bf(dinv[row] * r * hl[(size_t)row*128 + colv]);
        } else {
          float z  = sigm(Z[(size_t)row*256 + colv] + bz);
          float ht = tanhf(v + Z[(size_t)row*256 + 128 + colv] + bh);
          outp[(size_t)row*128 + colv] = z*hl[(size_t)row*128 + colv] + (1.f - z)*ht;
        }
      }
    }
  }
}

extern "C" void kernel_launch(void* const* d_in, const int* in_sizes, int n_in,
                              void* d_out, int out_size, void* d_ws, size_t ws_size,
                              hipStream_t stream){
  const float* x  = (const float*)d_in[0];
  const int*   ei = (const int*)d_in[1];
  const float* h  = (const float*)d_in[2];
  const float* Wx = (const float*)d_in[3];
  const float* bx = (const float*)d_in[4];
  const float* Wh = (const float*)d_in[5];
  const float* bh = (const float*)d_in[6];
  float* out = (float*)d_out;

  const int N = in_sizes[0] / 128;
  const int E = in_sizes[1] / 2;
  const int L = in_sizes[2] / in_sizes[0];
  const int* src = ei;
  const int* dst = ei + E;

  char* w = (char*)d_ws;
  auto alloc = [&](size_t b)->char*{ char* p = w; w += (b + 255) & ~(size_t)255; return p; };
  int* degi = (int*)alloc((size_t)2*N*sizeof(int)); int* cnt = degi + N;
  int* rowp = (int*)alloc((size_t)N*sizeof(int));
  int* part = (int*)alloc(256*sizeof(int));
  int* col  = (int*)alloc((size_t)E*sizeof(int));
  float* dinv = (float*)alloc((size_t)N*sizeof(float));
  unsigned short* WT = (unsigned short*)alloc((size_t)12*16384*sizeof(short));
  unsigned short* y2 = (unsigned short*)alloc((size_t)N*256*sizeof(short));
  unsigned short* ax = (unsigned short*)alloc((size_t)N*128*sizeof(short));
  unsigned short* ah = (unsigned short*)alloc((size_t)N*128*sizeof(short));
  unsigned short* yq = (unsigned short*)alloc((size_t)N*128*sizeof(short));
  unsigned short* aq = (unsigned short*)alloc((size_t)N*128*sizeof(short));
  float* Zpre = (float*)alloc((size_t)N*256*sizeof(float));

  const int NB = (N + 1023)/1024;
  const int gE = (E + 255)/256;
  const int gN = (N + 255)/256;
  const int gew = (N*32 + 255)/256;
  const int grows = (N + 127)/128;
  const int gagg4 = (N + 7)/8;     // NV=4: 8 nodes/block
  const int gagg2 = (N + 15)/16;   // NV=2: 16 nodes/block

  k_zero_int<<<(2*N+255)/256,256,0,stream>>>(degi, 2*N);
  k_hist<<<gE,256,0,stream>>>(dst, degi, E);
  k_dinv<<<gN,256,0,stream>>>(degi, dinv, N);
  k_scan_part<<<NB,256,0,stream>>>(degi, rowp, part, N);
  k_scan_top<<<1,64,0,stream>>>(part, NB);
  k_scan_add<<<NB,256,0,stream>>>(rowp, part, N);
  k_fill<<<gE,256,0,stream>>>(src, dst, rowp, cnt, col, E);
  k_prepw<<<(12*16384+255)/256,256,0,stream>>>(Wx, Wh, WT, 12*16384);

  for(int l=0; l<L; ++l){
    const float* inp = (l==0) ? x : (out + (size_t)(l-1)*N*128);
    const float* hl  = h + (size_t)l*N*128;
    const float* bxz = bx + (size_t)(l*3+0)*128; const float* bhz = bh + (size_t)(l*3+0)*128;
    const float* bxr = bx + (size_t)(l*3+1)*128; const float* bhr = bh + (size_t)(l*3+1)*128;
    const float* bxh = bx + (size_t)(l*3+2)*128; const float* bhh = bh + (size_t)(l*3+2)*128;
    const unsigned short* Wxz = WT + (size_t)(l*3+0)*16384;
    const unsigned short* Wxr = WT + (size_t)(l*3+1)*16384;
    const unsigned short* Wxh = WT + (size_t)(l*3+2)*16384;
    const unsigned short* Whz = WT + (size_t)(6+l*3+0)*16384;
    const unsigned short* Whr = WT + (size_t)(6+l*3+1)*16384;
    const unsigned short* Whh = WT + (size_t)(6+l*3+2)*16384;

    k_scale2<<<gew,256,0,stream>>>(inp, hl, dinv, y2, N);
    k_agg<4><<<gagg4,256,0,stream>>>(y2, rowp, degi, col, dinv, ax, ah, N);
    // z-pre: Z[:,0:128] = ax@Wxz + ah@Whz
    k_gemm<0><<<grows,256,0,stream>>>(ax, ah, Wxz, Whz, Zpre, 0,
                                      nullptr, nullptr, nullptr, nullptr, nullptr, nullptr,
                                      nullptr, nullptr, N);
    // r fused: yq = bf16(dinv * sigm(ax@Wxr + ah@Whr + bxr+bhr) * h)
    k_gemm<1><<<grows,256,0,stream>>>(ax, ah, Wxr, Whr, nullptr, 0,
                                      hl, dinv, bxr, bhr, nullptr, nullptr,
                                      yq, nullptr, N);
    // htpre partial: Z[:,128:256] = ax@Wxh
    k_gemm<0><<<grows,256,0,stream>>>(ax, nullptr, Wxh, nullptr, Zpre, 128,
                                      nullptr, nullptr, nullptr, nullptr, nullptr, nullptr,
                                      nullptr, nullptr, N);
    k_agg<2><<<gagg2,256,0,stream>>>(yq, rowp, degi, col, dinv, aq, nullptr, N);
    // final fused: out = z*h + (1-z)*tanh(aq@Whh + Z[:,128:256] + bxh+bhh)
    k_gemm<2><<<grows,256,0,stream>>>(aq, nullptr, Whh, nullptr, Zpre, 0,
                                      hl, dinv, bxz, bhz, bxh, bhh,
                                      nullptr, out + (size_t)l*N*128, N);
  }
}